// Round 5
// baseline (254.321 us; speedup 1.0000x reference)
//
#include <hip/hip_runtime.h>
#include <math.h>

#define BSZ 2
#define CDIM 256
#define LSEQ 4096
#define DIN 512
#define NST 16
#define NC 128
#define CT 32
#define LOG2E 1.44269504088896f

typedef unsigned short ushort_t;
typedef short s16x8 __attribute__((ext_vector_type(8)));
typedef float f32x4 __attribute__((ext_vector_type(4)));

__device__ inline ushort_t f2bf(float f) {
    union { float f; unsigned u; } v; v.f = f;
    unsigned r = v.u + 0x7FFF + ((v.u >> 16) & 1);
    return (ushort_t)(r >> 16);
}
__device__ inline float bf2f(ushort_t u) {
    union { unsigned u; float f; } v; v.u = ((unsigned)u) << 16;
    return v.f;
}

// ---------------- prep + layernorm in one kernel ----------------
// bi 0..255   : LayerNorm tile (b = bi>>7, l0 = (bi&127)*32)
// bi 256..511 : W_in (256,1024) -> Wt1 (1024,256) bf16
// bi 512..639 : W_out (512,256) -> Wt3 (256,512) bf16
// bi 640..735 : W_x (512,48)    -> Wxt (48,512) bf16
__device__ inline void tile_tr(const float* __restrict__ src, ushort_t* __restrict__ dst,
                               int R, int C, int c0, int r0, int tid) {
    __shared__ float T[32][33];
    int tx = tid & 31, ty = tid >> 5;
    #pragma unroll
    for (int i = 0; i < 4; ++i)
        T[ty + i * 8][tx] = src[(r0 + ty + i * 8) * C + c0 + tx];
    __syncthreads();
    #pragma unroll
    for (int i = 0; i < 4; ++i)
        dst[(c0 + ty + i * 8) * R + r0 + tx] = f2bf(T[tx][ty + i * 8]);
}

__global__ __launch_bounds__(256) void k_prep(const float* __restrict__ x,
                                              const float* __restrict__ g,
                                              const float* __restrict__ beta,
                                              const float* __restrict__ W_in,
                                              const float* __restrict__ W_out,
                                              const float* __restrict__ W_x,
                                              ushort_t* __restrict__ xsb,
                                              ushort_t* __restrict__ Wt1,
                                              ushort_t* __restrict__ Wt3,
                                              ushort_t* __restrict__ Wxt) {
    int bi = blockIdx.x, tid = threadIdx.x;
    if (bi >= 256) {
        if (bi < 512) {
            int rem = bi - 256;
            tile_tr(W_in, Wt1, 256, 1024, (rem & 31) * 32, (rem >> 5) * 32, tid);
        } else if (bi < 640) {
            int rem = bi - 512;
            tile_tr(W_out, Wt3, 512, 256, (rem & 7) * 32, (rem >> 3) * 32, tid);
        } else {
            int f = (bi - 640) * 256 + tid;
            int n = f >> 9, dcol = f & 511;
            Wxt[n * 512 + dcol] = f2bf(W_x[dcol * 48 + n]);
        }
        return;
    }
    // ---- LayerNorm ----
    int b  = bi >> 7;
    int l0 = (bi & 127) * 32;
    __shared__ float T[256][33];
    __shared__ float ps[8][32], ps2[8][32];
    __shared__ float mus[32], rs[32];
    #pragma unroll
    for (int i = 0; i < 8; ++i) {
        int f = i * 256 + tid;
        int c = f >> 3, lq = f & 7;
        float4 v = *(const float4*)(x + (b * 256 + c) * 4096 + l0 + lq * 4);
        T[c][lq * 4 + 0] = v.x; T[c][lq * 4 + 1] = v.y;
        T[c][lq * 4 + 2] = v.z; T[c][lq * 4 + 3] = v.w;
    }
    __syncthreads();
    {
        int lt = tid & 31, q = tid >> 5;
        float s = 0.f, s2 = 0.f;
        #pragma unroll
        for (int c = q * 32; c < q * 32 + 32; ++c) {
            float v = T[c][lt];
            s += v; s2 += v * v;
        }
        ps[q][lt] = s; ps2[q][lt] = s2;
    }
    __syncthreads();
    if (tid < 32) {
        float ts = 0.f, ts2 = 0.f;
        #pragma unroll
        for (int q = 0; q < 8; ++q) { ts += ps[q][tid]; ts2 += ps2[q][tid]; }
        float mu  = ts * (1.f / 256.f);
        float var = ts2 * (1.f / 256.f) - mu * mu;
        mus[tid] = mu;
        rs[tid]  = rsqrtf(var + 1e-5f);
    }
    __syncthreads();
    float gg = g[tid], bb = beta[tid];
    #pragma unroll
    for (int i = 0; i < 32; ++i) {
        float v = (T[tid][i] - mus[i]) * rs[i] * gg + bb;
        xsb[(b * 4096 + l0 + i) * 256 + tid] = f2bf(v);
    }
}

// ---------------- GEMM1 (MFMA bf16): xz = xs @ W_in -> bf16 xin,z ----------
__global__ __launch_bounds__(256) void k_gemm1(const ushort_t* __restrict__ Abf,
                                               const ushort_t* __restrict__ Wt,
                                               ushort_t* __restrict__ xinb,
                                               ushort_t* __restrict__ zb) {
    __shared__ ushort_t As[128][40];
    __shared__ ushort_t Bs[128][40];
    int tid = threadIdx.x;
    int m0 = blockIdx.x * 128;
    int n0 = blockIdx.y * 128;
    int lane = tid & 63, w = tid >> 6;
    int wr = w >> 1, wc = w & 1;
    int quad = lane >> 4, lm = lane & 15;
    f32x4 acc[4][4] = {};
    for (int k0 = 0; k0 < 256; k0 += 32) {
        #pragma unroll
        for (int i = 0; i < 2; ++i) {
            int c = i * 256 + tid;
            int r = c >> 2, kq = c & 3;
            *(uint4*)&As[r][kq * 8] = *(const uint4*)&Abf[(m0 + r) * 256 + k0 + kq * 8];
            *(uint4*)&Bs[r][kq * 8] = *(const uint4*)&Wt[(n0 + r) * 256 + k0 + kq * 8];
        }
        __syncthreads();
        s16x8 af[4], bf_[4];
        #pragma unroll
        for (int mi = 0; mi < 4; ++mi)
            af[mi] = *(const s16x8*)&As[wr * 64 + mi * 16 + lm][quad * 8];
        #pragma unroll
        for (int ni = 0; ni < 4; ++ni)
            bf_[ni] = *(const s16x8*)&Bs[wc * 64 + ni * 16 + lm][quad * 8];
        #pragma unroll
        for (int mi = 0; mi < 4; ++mi)
            #pragma unroll
            for (int ni = 0; ni < 4; ++ni)
                acc[mi][ni] = __builtin_amdgcn_mfma_f32_16x16x32_bf16(
                    af[mi], bf_[ni], acc[mi][ni], 0, 0, 0);
        __syncthreads();
    }
    bool isz = (n0 >= 512);
    ushort_t* out = isz ? zb : xinb;
    int nb = isz ? n0 - 512 : n0;
    #pragma unroll
    for (int mi = 0; mi < 4; ++mi) {
        #pragma unroll
        for (int ni = 0; ni < 4; ++ni) {
            int colg = nb + wc * 64 + ni * 16 + lm;
            #pragma unroll
            for (int r = 0; r < 4; ++r) {
                int rowg = m0 + wr * 64 + mi * 16 + quad * 4 + r;
                out[rowg * 512 + colg] = f2bf(acc[mi][ni][r]);
            }
        }
    }
}

// ---------------- depthwise causal conv(4) + SiLU -> bf16 xcb --------------
__global__ __launch_bounds__(256) void k_conv(const ushort_t* __restrict__ xinb,
                                              const float* __restrict__ cw,
                                              const float* __restrict__ cb,
                                              ushort_t* __restrict__ xcb) {
    int idx = blockIdx.x * 256 + threadIdx.x;
    int d = idx & 511;
    int r = idx >> 9;
    int l = r & 4095;
    int b = r >> 12;
    float s = cb[d];
    #pragma unroll
    for (int k = 0; k < 4; ++k) {
        int ll = l - 3 + k;
        if (ll >= 0) s += cw[d * 4 + k] * bf2f(xinb[(((b << 12) + ll) << 9) + d]);
    }
    float sig = 1.f / (1.f + expf(-s));
    xcb[idx] = f2bf(s * sig);
}

// ---------------- x-proj (MFMA) + fused dt-proj ----------------
// dbl = xc @ W_x; Bm/Cm from cols 16..47; dt = softplus(dbl[:, :16] @ W_dt + b_dt)
// A: xcb (8192,512) bf16. B: Wxt (48,512) bf16. BM=64, grid 128.
__global__ __launch_bounds__(256) void k_xproj(const ushort_t* __restrict__ xcb,
                                               const ushort_t* __restrict__ Wxt,
                                               const float* __restrict__ Wdt,
                                               const float* __restrict__ bdt,
                                               ushort_t* __restrict__ dtp,
                                               float* __restrict__ Bm,
                                               float* __restrict__ Cm) {
    __shared__ ushort_t As[64][72];
    __shared__ ushort_t Bs[48][72];
    __shared__ float sWdt[16][512];
    __shared__ float dbl[64][17];
    int tid = threadIdx.x;
    int m0 = blockIdx.x * 64;
    int lane = tid & 63, w = tid >> 6;
    int quad = lane >> 4, lm = lane & 15;
    // stage W_dt (16x512 fp32) once
    #pragma unroll
    for (int i = 0; i < 32; ++i)
        ((float*)sWdt)[i * 256 + tid] = Wdt[i * 256 + tid];
    f32x4 acc[3] = {};
    for (int k0 = 0; k0 < 512; k0 += 64) {
        #pragma unroll
        for (int i = 0; i < 2; ++i) {
            int f = i * 256 + tid;
            int r = f >> 3, kq = f & 7;
            *(uint4*)&As[r][kq * 8] = *(const uint4*)&xcb[(m0 + r) * 512 + k0 + kq * 8];
        }
        if (tid < 192) {
            #pragma unroll
            for (int i = 0; i < 2; ++i) {
                int f = i * 192 + tid;
                int r = f >> 3, kq = f & 7;
                *(uint4*)&Bs[r][kq * 8] = *(const uint4*)&Wxt[r * 512 + k0 + kq * 8];
            }
        }
        __syncthreads();
        #pragma unroll
        for (int kk = 0; kk < 2; ++kk) {
            s16x8 af = *(const s16x8*)&As[w * 16 + lm][kk * 32 + quad * 8];
            #pragma unroll
            for (int nt = 0; nt < 3; ++nt) {
                s16x8 bv = *(const s16x8*)&Bs[nt * 16 + lm][kk * 32 + quad * 8];
                acc[nt] = __builtin_amdgcn_mfma_f32_16x16x32_bf16(af, bv, acc[nt], 0, 0, 0);
            }
        }
        __syncthreads();
    }
    // Bm/Cm direct store; dtr -> LDS
    #pragma unroll
    for (int r = 0; r < 4; ++r) {
        int row = m0 + w * 16 + quad * 4 + r;
        Bm[row * 16 + lm] = acc[1][r];
        Cm[row * 16 + lm] = acc[2][r];
        dbl[w * 16 + quad * 4 + r][lm] = acc[0][r];
    }
    __syncthreads();
    // dt-proj: 64 rows x 512 cols; thread handles col tid and tid+256
    float b0 = bdt[tid], b1 = bdt[256 + tid];
    for (int row = 0; row < 64; ++row) {
        float s0 = b0, s1 = b1;
        #pragma unroll
        for (int r = 0; r < 16; ++r) {
            float dv = dbl[row][r];
            s0 += dv * sWdt[r][tid];
            s1 += dv * sWdt[r][tid + 256];
        }
        s0 = (s0 > 20.f) ? s0 : log1pf(expf(s0));
        s1 = (s1 > 20.f) ? s1 : log1pf(expf(s1));
        int base = (m0 + row) * 512;
        dtp[base + tid] = f2bf(s0);
        dtp[base + tid + 256] = f2bf(s1);
    }
}

// ---------------- scan phase A: S layout [b][c][n][d] ----------------
__global__ __launch_bounds__(512) void k_scanA(const ushort_t* __restrict__ dtp,
                                               const ushort_t* __restrict__ xcb,
                                               const float* __restrict__ Bm,
                                               const float* __restrict__ A_log,
                                               float* __restrict__ S,
                                               float* __restrict__ sdt) {
    int b = blockIdx.x >> 7;
    int ch = blockIdx.x & 127;
    int d = threadIdx.x;
    __shared__ float Bb[CT][16];
    {
        int t = threadIdx.x >> 4, n = threadIdx.x & 15;
        Bb[t][n] = Bm[((b << 12) + ch * CT + t) * 16 + n];
    }
    __syncthreads();
    float a2[16];
    #pragma unroll
    for (int n = 0; n < 16; ++n) a2[n] = -expf(A_log[d * 16 + n]) * LOG2E;
    float h[16] = {};
    float sum_dt = 0.f;
    int base = ((b << 12) + ch * CT) * 512 + d;
    for (int t = 0; t < CT; ++t) {
        float dv = bf2f(dtp[base + t * 512]);
        float xv = bf2f(xcb[base + t * 512]);
        sum_dt += dv;
        float dx = dv * xv;
        #pragma unroll
        for (int n = 0; n < 16; ++n) {
            float w = exp2f(dv * a2[n]);
            h[n] = w * h[n] + dx * Bb[t][n];
        }
    }
    int so = ((b * NC + ch) * 16) * 512 + d;
    #pragma unroll
    for (int n = 0; n < 16; ++n)
        S[so + n * 512] = h[n];
    sdt[(b * NC + ch) * 512 + d] = sum_dt;
}

// ---------------- comb phase A: per-segment compose (16 chunks) ------------
__global__ __launch_bounds__(512) void k_combA(const float* __restrict__ S,
                                               const float* __restrict__ sdt,
                                               const float* __restrict__ A_log,
                                               float* __restrict__ Wsg,
                                               float* __restrict__ Ssg) {
    int bi = blockIdx.x;
    int b = bi >> 7, n = (bi >> 3) & 15, seg = bi & 7;
    int d = threadIdx.x;
    float a2 = -expf(A_log[d * 16 + n]) * LOG2E;
    float Wc = 1.f, Sc = 0.f;
    #pragma unroll
    for (int i = 0; i < 16; ++i) {
        int c = seg * 16 + i;
        float w = exp2f(a2 * sdt[(b * NC + c) * 512 + d]);
        float s = S[((b * NC + c) * 16 + n) * 512 + d];
        Sc = w * Sc + s;
        Wc *= w;
    }
    int o = ((b * 16 + n) * 8 + seg) * 512 + d;
    Wsg[o] = Wc;
    Ssg[o] = Sc;
}

// ---------------- comb phase C (fused prefix): hinit in place in S ---------
__global__ __launch_bounds__(512) void k_combC(float* S,
                                               const float* __restrict__ sdt,
                                               const float* __restrict__ A_log,
                                               const float* __restrict__ Wsg,
                                               const float* __restrict__ Ssg) {
    int bi = blockIdx.x;
    int b = bi >> 7, n = (bi >> 3) & 15, seg = bi & 7;
    int d = threadIdx.x;
    float a2 = -expf(A_log[d * 16 + n]) * LOG2E;
    // segment prefix (<=7 steps)
    float h = 0.f;
    int o0 = ((b * 16 + n) * 8) * 512 + d;
    for (int s = 0; s < seg; ++s)
        h = Wsg[o0 + s * 512] * h + Ssg[o0 + s * 512];
    #pragma unroll
    for (int i = 0; i < 16; ++i) {
        int c = seg * 16 + i;
        int si = ((b * NC + c) * 16 + n) * 512 + d;
        float w = exp2f(a2 * sdt[(b * NC + c) * 512 + d]);
        float sval = S[si];
        S[si] = h;
        h = w * h + sval;
    }
}

// ---------------- scan phase C: replay + skip + SiLU gate -> bf16 ----------
__global__ __launch_bounds__(512) void k_scanC(const ushort_t* __restrict__ dtp,
                                               const ushort_t* __restrict__ xcb,
                                               const float* __restrict__ Bm,
                                               const float* __restrict__ Cm,
                                               const float* __restrict__ A_log,
                                               const float* __restrict__ hinit,
                                               const float* __restrict__ Dskip,
                                               const ushort_t* __restrict__ zb,
                                               ushort_t* __restrict__ yact) {
    int b = blockIdx.x >> 7;
    int ch = blockIdx.x & 127;
    int d = threadIdx.x;
    __shared__ float Bb[CT][16], Cb[CT][16];
    {
        int t = threadIdx.x >> 4, n = threadIdx.x & 15;
        int li = ((b << 12) + ch * CT + t) * 16 + n;
        Bb[t][n] = Bm[li];
        Cb[t][n] = Cm[li];
    }
    __syncthreads();
    float a2[16], h[16];
    #pragma unroll
    for (int n = 0; n < 16; ++n) a2[n] = -expf(A_log[d * 16 + n]) * LOG2E;
    int hi = ((b * NC + ch) * 16) * 512 + d;
    #pragma unroll
    for (int n = 0; n < 16; ++n) h[n] = hinit[hi + n * 512];
    float Dsk = Dskip[d];
    int base = ((b << 12) + ch * CT) * 512 + d;
    for (int t = 0; t < CT; ++t) {
        float dv = bf2f(dtp[base + t * 512]);
        float xv = bf2f(xcb[base + t * 512]);
        float zv = bf2f(zb[base + t * 512]);
        float dx = dv * xv;
        float y = 0.f;
        #pragma unroll
        for (int n = 0; n < 16; ++n) {
            float w = exp2f(dv * a2[n]);
            h[n] = w * h[n] + dx * Bb[t][n];
            y += h[n] * Cb[t][n];
        }
        y += xv * Dsk;
        float sig = 1.f / (1.f + expf(-zv));
        yact[base + t * 512] = f2bf(y * zv * sig);
    }
}

// ---------------- GEMM3 (MFMA bf16): out = yact @ W_out, transposed store --
__global__ __launch_bounds__(256) void k_gemm3(const ushort_t* __restrict__ Abf,
                                               const ushort_t* __restrict__ Wt3,
                                               float* __restrict__ out) {
    __shared__ ushort_t As[128][40];
    __shared__ ushort_t Bs[64][40];
    __shared__ float T[64][132];
    int tid = threadIdx.x;
    int m0 = blockIdx.x * 128;
    int n0 = blockIdx.y * 64;
    int lane = tid & 63, w = tid >> 6;
    int wr = w >> 1, wc = w & 1;
    int quad = lane >> 4, lm = lane & 15;
    f32x4 acc[4][2] = {};
    for (int k0 = 0; k0 < 512; k0 += 32) {
        #pragma unroll
        for (int i = 0; i < 2; ++i) {
            int c = i * 256 + tid;
            int r = c >> 2, kq = c & 3;
            *(uint4*)&As[r][kq * 8] = *(const uint4*)&Abf[(m0 + r) * 512 + k0 + kq * 8];
        }
        {
            int r = tid >> 2, kq = tid & 3;
            *(uint4*)&Bs[r][kq * 8] = *(const uint4*)&Wt3[(n0 + r) * 512 + k0 + kq * 8];
        }
        __syncthreads();
        s16x8 af[4], bf_[2];
        #pragma unroll
        for (int mi = 0; mi < 4; ++mi)
            af[mi] = *(const s16x8*)&As[wr * 64 + mi * 16 + lm][quad * 8];
        #pragma unroll
        for (int ni = 0; ni < 2; ++ni)
            bf_[ni] = *(const s16x8*)&Bs[wc * 32 + ni * 16 + lm][quad * 8];
        #pragma unroll
        for (int mi = 0; mi < 4; ++mi)
            #pragma unroll
            for (int ni = 0; ni < 2; ++ni)
                acc[mi][ni] = __builtin_amdgcn_mfma_f32_16x16x32_bf16(
                    af[mi], bf_[ni], acc[mi][ni], 0, 0, 0);
        __syncthreads();
    }
    #pragma unroll
    for (int mi = 0; mi < 4; ++mi)
        #pragma unroll
        for (int ni = 0; ni < 2; ++ni)
            #pragma unroll
            for (int r = 0; r < 4; ++r)
                T[wc * 32 + ni * 16 + lm][wr * 64 + mi * 16 + quad * 4 + r] = acc[mi][ni][r];
    __syncthreads();
    int b = m0 >> 12;
    int l0 = m0 & 4095;
    #pragma unroll
    for (int i = 0; i < 8; ++i) {
        int f = i * 256 + tid;
        int col = f >> 5, lq = f & 31;
        float4 v = *(float4*)&T[col][lq * 4];
        *(float4*)(out + b * (256 * 4096) + (n0 + col) * 4096 + l0 + lq * 4) = v;
    }
}

extern "C" void kernel_launch(void* const* d_in, const int* in_sizes, int n_in,
                              void* d_out, int out_size, void* d_ws, size_t ws_size,
                              hipStream_t stream) {
    const float* x      = (const float*)d_in[0];
    const float* ln_g   = (const float*)d_in[1];
    const float* ln_b   = (const float*)d_in[2];
    const float* W_in   = (const float*)d_in[3];
    const float* conv_w = (const float*)d_in[4];
    const float* conv_b = (const float*)d_in[5];
    const float* W_x    = (const float*)d_in[6];
    const float* W_dt   = (const float*)d_in[7];
    const float* b_dt   = (const float*)d_in[8];
    const float* A_log  = (const float*)d_in[9];
    const float* D_skip = (const float*)d_in[10];
    const float* W_out  = (const float*)d_in[11];
    float* out = (float*)d_out;

    float* ws = (float*)d_ws;
    float* Bm   = ws;                      // 131,072 f
    float* Cm   = Bm + 131072;             // 131,072 f
    float* Sst  = Cm + 131072;             // 2,097,152 f (hinit in place)
    float* sdt  = Sst + 2097152;           // 131,072 f
    float* Wsg  = sdt + 131072;            // 131,072 f
    float* Ssg  = Wsg + 131072;            // 131,072 f
    ushort_t* xs_bf = (ushort_t*)(Ssg + 131072);   // 2,097,152 us
    ushort_t* Wt1  = xs_bf + 2097152;      // 262,144 us
    ushort_t* Wt3  = Wt1 + 262144;         // 131,072 us
    ushort_t* Wxt  = Wt3 + 131072;         // 24,576 us (pad to 32,768)
    ushort_t* xinb = Wxt + 32768;          // 4,194,304 us
    ushort_t* zb   = xinb + 4194304;       // 4,194,304 us
    ushort_t* xcb  = zb + 4194304;         // 4,194,304 us
    ushort_t* dtp  = xcb + 4194304;        // 4,194,304 us
    ushort_t* yact = xinb;                 // alias: xinb dead after conv

    k_prep <<<dim3(736),   dim3(256), 0, stream>>>(x, ln_g, ln_b, W_in, W_out, W_x,
                                                   xs_bf, Wt1, Wt3, Wxt);
    k_gemm1<<<dim3(64, 8), dim3(256), 0, stream>>>(xs_bf, Wt1, xinb, zb);
    k_conv <<<dim3(16384), dim3(256), 0, stream>>>(xinb, conv_w, conv_b, xcb);
    k_xproj<<<dim3(128),   dim3(256), 0, stream>>>(xcb, Wxt, W_dt, b_dt, dtp, Bm, Cm);
    k_scanA<<<dim3(256),   dim3(512), 0, stream>>>(dtp, xcb, Bm, A_log, Sst, sdt);
    k_combA<<<dim3(256),   dim3(512), 0, stream>>>(Sst, sdt, A_log, Wsg, Ssg);
    k_combC<<<dim3(256),   dim3(512), 0, stream>>>(Sst, sdt, A_log, Wsg, Ssg);
    k_scanC<<<dim3(256),   dim3(512), 0, stream>>>(dtp, xcb, Bm, Cm, A_log, Sst,
                                                   D_skip, zb, yact);
    k_gemm3<<<dim3(64, 4), dim3(256), 0, stream>>>(yact, Wt3, out);
}

// Round 6
// 228.568 us; speedup vs baseline: 1.1127x; 1.1127x over previous
//
#include <hip/hip_runtime.h>
#include <math.h>

#define BSZ 2
#define CDIM 256
#define LSEQ 4096
#define DIN 512
#define NST 16
#define NC 128
#define CT 32
#define LOG2E 1.44269504088896f

typedef unsigned short ushort_t;
typedef short s16x8 __attribute__((ext_vector_type(8)));
typedef float f32x4 __attribute__((ext_vector_type(4)));

__device__ inline ushort_t f2bf(float f) {
    union { float f; unsigned u; } v; v.f = f;
    unsigned r = v.u + 0x7FFF + ((v.u >> 16) & 1);
    return (ushort_t)(r >> 16);
}
__device__ inline float bf2f(ushort_t u) {
    union { unsigned u; float f; } v; v.u = ((unsigned)u) << 16;
    return v.f;
}

// ---------------- prep + layernorm in one kernel ----------------
__device__ inline void tile_tr(const float* __restrict__ src, ushort_t* __restrict__ dst,
                               int R, int C, int c0, int r0, int tid) {
    __shared__ float T[32][33];
    int tx = tid & 31, ty = tid >> 5;
    #pragma unroll
    for (int i = 0; i < 4; ++i)
        T[ty + i * 8][tx] = src[(r0 + ty + i * 8) * C + c0 + tx];
    __syncthreads();
    #pragma unroll
    for (int i = 0; i < 4; ++i)
        dst[(c0 + ty + i * 8) * R + r0 + tx] = f2bf(T[tx][ty + i * 8]);
}

__global__ __launch_bounds__(256) void k_prep(const float* __restrict__ x,
                                              const float* __restrict__ g,
                                              const float* __restrict__ beta,
                                              const float* __restrict__ W_in,
                                              const float* __restrict__ W_out,
                                              const float* __restrict__ W_x,
                                              ushort_t* __restrict__ xsb,
                                              ushort_t* __restrict__ Wt1,
                                              ushort_t* __restrict__ Wt3,
                                              ushort_t* __restrict__ Wxt) {
    int bi = blockIdx.x, tid = threadIdx.x;
    if (bi >= 256) {
        if (bi < 512) {
            int rem = bi - 256;
            tile_tr(W_in, Wt1, 256, 1024, (rem & 31) * 32, (rem >> 5) * 32, tid);
        } else if (bi < 640) {
            int rem = bi - 512;
            tile_tr(W_out, Wt3, 512, 256, (rem & 7) * 32, (rem >> 3) * 32, tid);
        } else {
            int f = (bi - 640) * 256 + tid;
            int n = f >> 9, dcol = f & 511;
            Wxt[n * 512 + dcol] = f2bf(W_x[dcol * 48 + n]);
        }
        return;
    }
    int b  = bi >> 7;
    int l0 = (bi & 127) * 32;
    __shared__ float T[256][33];
    __shared__ float ps[8][32], ps2[8][32];
    __shared__ float mus[32], rs[32];
    #pragma unroll
    for (int i = 0; i < 8; ++i) {
        int f = i * 256 + tid;
        int c = f >> 3, lq = f & 7;
        float4 v = *(const float4*)(x + (b * 256 + c) * 4096 + l0 + lq * 4);
        T[c][lq * 4 + 0] = v.x; T[c][lq * 4 + 1] = v.y;
        T[c][lq * 4 + 2] = v.z; T[c][lq * 4 + 3] = v.w;
    }
    __syncthreads();
    {
        int lt = tid & 31, q = tid >> 5;
        float s = 0.f, s2 = 0.f;
        #pragma unroll
        for (int c = q * 32; c < q * 32 + 32; ++c) {
            float v = T[c][lt];
            s += v; s2 += v * v;
        }
        ps[q][lt] = s; ps2[q][lt] = s2;
    }
    __syncthreads();
    if (tid < 32) {
        float ts = 0.f, ts2 = 0.f;
        #pragma unroll
        for (int q = 0; q < 8; ++q) { ts += ps[q][tid]; ts2 += ps2[q][tid]; }
        float mu  = ts * (1.f / 256.f);
        float var = ts2 * (1.f / 256.f) - mu * mu;
        mus[tid] = mu;
        rs[tid]  = rsqrtf(var + 1e-5f);
    }
    __syncthreads();
    float gg = g[tid], bb = beta[tid];
    #pragma unroll
    for (int i = 0; i < 32; ++i) {
        float v = (T[tid][i] - mus[i]) * rs[i] * gg + bb;
        xsb[(b * 4096 + l0 + i) * 256 + tid] = f2bf(v);
    }
}

// ---------------- GEMM1 (MFMA bf16): xz = xs @ W_in -> bf16 xin,z ----------
__global__ __launch_bounds__(256) void k_gemm1(const ushort_t* __restrict__ Abf,
                                               const ushort_t* __restrict__ Wt,
                                               ushort_t* __restrict__ xinb,
                                               ushort_t* __restrict__ zb) {
    __shared__ ushort_t As[128][40];
    __shared__ ushort_t Bs[128][40];
    int tid = threadIdx.x;
    int m0 = blockIdx.x * 128;
    int n0 = blockIdx.y * 128;
    int lane = tid & 63, w = tid >> 6;
    int wr = w >> 1, wc = w & 1;
    int quad = lane >> 4, lm = lane & 15;
    f32x4 acc[4][4] = {};
    for (int k0 = 0; k0 < 256; k0 += 32) {
        #pragma unroll
        for (int i = 0; i < 2; ++i) {
            int c = i * 256 + tid;
            int r = c >> 2, kq = c & 3;
            *(uint4*)&As[r][kq * 8] = *(const uint4*)&Abf[(m0 + r) * 256 + k0 + kq * 8];
            *(uint4*)&Bs[r][kq * 8] = *(const uint4*)&Wt[(n0 + r) * 256 + k0 + kq * 8];
        }
        __syncthreads();
        s16x8 af[4], bf_[4];
        #pragma unroll
        for (int mi = 0; mi < 4; ++mi)
            af[mi] = *(const s16x8*)&As[wr * 64 + mi * 16 + lm][quad * 8];
        #pragma unroll
        for (int ni = 0; ni < 4; ++ni)
            bf_[ni] = *(const s16x8*)&Bs[wc * 64 + ni * 16 + lm][quad * 8];
        #pragma unroll
        for (int mi = 0; mi < 4; ++mi)
            #pragma unroll
            for (int ni = 0; ni < 4; ++ni)
                acc[mi][ni] = __builtin_amdgcn_mfma_f32_16x16x32_bf16(
                    af[mi], bf_[ni], acc[mi][ni], 0, 0, 0);
        __syncthreads();
    }
    bool isz = (n0 >= 512);
    ushort_t* out = isz ? zb : xinb;
    int nb = isz ? n0 - 512 : n0;
    #pragma unroll
    for (int mi = 0; mi < 4; ++mi) {
        #pragma unroll
        for (int ni = 0; ni < 4; ++ni) {
            int colg = nb + wc * 64 + ni * 16 + lm;
            #pragma unroll
            for (int r = 0; r < 4; ++r) {
                int rowg = m0 + wr * 64 + mi * 16 + quad * 4 + r;
                out[rowg * 512 + colg] = f2bf(acc[mi][ni][r]);
            }
        }
    }
}

// ---------------- depthwise causal conv(4) + SiLU -> bf16 xcb --------------
__global__ __launch_bounds__(256) void k_conv(const ushort_t* __restrict__ xinb,
                                              const float* __restrict__ cw,
                                              const float* __restrict__ cb,
                                              ushort_t* __restrict__ xcb) {
    int idx = blockIdx.x * 256 + threadIdx.x;
    int d = idx & 511;
    int r = idx >> 9;
    int l = r & 4095;
    int b = r >> 12;
    float s = cb[d];
    #pragma unroll
    for (int k = 0; k < 4; ++k) {
        int ll = l - 3 + k;
        if (ll >= 0) s += cw[d * 4 + k] * bf2f(xinb[(((b << 12) + ll) << 9) + d]);
    }
    float sig = 1.f / (1.f + expf(-s));
    xcb[idx] = f2bf(s * sig);
}

// ---------------- x-proj (MFMA): dbl = xc @ W_x -> dtr/Bm/Cm ---------------
__global__ __launch_bounds__(256) void k_xproj1(const ushort_t* __restrict__ xcb,
                                                const ushort_t* __restrict__ Wxt,
                                                float* __restrict__ dtr,
                                                float* __restrict__ Bm,
                                                float* __restrict__ Cm) {
    __shared__ ushort_t As[64][72];
    __shared__ ushort_t Bs[48][72];
    int tid = threadIdx.x;
    int m0 = blockIdx.x * 64;
    int lane = tid & 63, w = tid >> 6;
    int quad = lane >> 4, lm = lane & 15;
    f32x4 acc[3] = {};
    for (int k0 = 0; k0 < 512; k0 += 64) {
        #pragma unroll
        for (int i = 0; i < 2; ++i) {
            int f = i * 256 + tid;
            int r = f >> 3, kq = f & 7;
            *(uint4*)&As[r][kq * 8] = *(const uint4*)&xcb[(m0 + r) * 512 + k0 + kq * 8];
        }
        if (tid < 192) {
            #pragma unroll
            for (int i = 0; i < 2; ++i) {
                int f = i * 192 + tid;
                int r = f >> 3, kq = f & 7;
                *(uint4*)&Bs[r][kq * 8] = *(const uint4*)&Wxt[r * 512 + k0 + kq * 8];
            }
        }
        __syncthreads();
        #pragma unroll
        for (int kk = 0; kk < 2; ++kk) {
            s16x8 af = *(const s16x8*)&As[w * 16 + lm][kk * 32 + quad * 8];
            #pragma unroll
            for (int nt = 0; nt < 3; ++nt) {
                s16x8 bv = *(const s16x8*)&Bs[nt * 16 + lm][kk * 32 + quad * 8];
                acc[nt] = __builtin_amdgcn_mfma_f32_16x16x32_bf16(af, bv, acc[nt], 0, 0, 0);
            }
        }
        __syncthreads();
    }
    #pragma unroll
    for (int nt = 0; nt < 3; ++nt) {
        float* dst = (nt == 0) ? dtr : ((nt == 1) ? Bm : Cm);
        #pragma unroll
        for (int r = 0; r < 4; ++r) {
            int row = m0 + w * 16 + quad * 4 + r;
            dst[row * 16 + lm] = acc[nt][r];
        }
    }
}

// ---------------- dt-proj: dtp = softplus(dtr @ W_dt + b_dt) -> bf16 -------
__global__ __launch_bounds__(256) void k_dtproj(const float* __restrict__ dtr,
                                                const float* __restrict__ Wdt,
                                                const float* __restrict__ bdt,
                                                ushort_t* __restrict__ dtp) {
    int tid = threadIdx.x;
    int t0 = blockIdx.x * 16;
    __shared__ float R[16][17];
    float w0[16], w1[16];
    #pragma unroll
    for (int r = 0; r < 16; ++r) {
        w0[r] = Wdt[r * 512 + tid];
        w1[r] = Wdt[r * 512 + 256 + tid];
    }
    float b0 = bdt[tid], b1 = bdt[256 + tid];
    {
        int t = tid >> 4, r = tid & 15;
        R[t][r] = dtr[(t0 + t) * 16 + r];
    }
    __syncthreads();
    for (int t = 0; t < 16; ++t) {
        float s0 = b0, s1 = b1;
        #pragma unroll
        for (int r = 0; r < 16; ++r) {
            float dv = R[t][r];
            s0 += dv * w0[r];
            s1 += dv * w1[r];
        }
        s0 = (s0 > 20.f) ? s0 : log1pf(expf(s0));
        s1 = (s1 > 20.f) ? s1 : log1pf(expf(s1));
        dtp[(t0 + t) * 512 + tid] = f2bf(s0);
        dtp[(t0 + t) * 512 + 256 + tid] = f2bf(s1);
    }
}

// ---------------- scan phase A: S layout [b][c][n][d] ----------------
__global__ __launch_bounds__(512) void k_scanA(const ushort_t* __restrict__ dtp,
                                               const ushort_t* __restrict__ xcb,
                                               const float* __restrict__ Bm,
                                               const float* __restrict__ A_log,
                                               float* __restrict__ S,
                                               float* __restrict__ sdt) {
    int b = blockIdx.x >> 7;
    int ch = blockIdx.x & 127;
    int d = threadIdx.x;
    __shared__ float Bb[CT][16];
    {
        int t = threadIdx.x >> 4, n = threadIdx.x & 15;
        Bb[t][n] = Bm[((b << 12) + ch * CT + t) * 16 + n];
    }
    __syncthreads();
    float a2[16];
    #pragma unroll
    for (int n = 0; n < 16; ++n) a2[n] = -expf(A_log[d * 16 + n]) * LOG2E;
    float h[16] = {};
    float sum_dt = 0.f;
    int base = ((b << 12) + ch * CT) * 512 + d;
    for (int t = 0; t < CT; ++t) {
        float dv = bf2f(dtp[base + t * 512]);
        float xv = bf2f(xcb[base + t * 512]);
        sum_dt += dv;
        float dx = dv * xv;
        #pragma unroll
        for (int n = 0; n < 16; ++n) {
            float w = exp2f(dv * a2[n]);
            h[n] = w * h[n] + dx * Bb[t][n];
        }
    }
    int so = ((b * NC + ch) * 16) * 512 + d;
    #pragma unroll
    for (int n = 0; n < 16; ++n)
        S[so + n * 512] = h[n];
    sdt[(b * NC + ch) * 512 + d] = sum_dt;
}

// ---------------- comb phase A: per-segment compose (16 chunks) ------------
__global__ __launch_bounds__(512) void k_combA(const float* __restrict__ S,
                                               const float* __restrict__ sdt,
                                               const float* __restrict__ A_log,
                                               float* __restrict__ Wsg,
                                               float* __restrict__ Ssg) {
    int bi = blockIdx.x;
    int b = bi >> 7, n = (bi >> 3) & 15, seg = bi & 7;
    int d = threadIdx.x;
    float a2 = -expf(A_log[d * 16 + n]) * LOG2E;
    float Wc = 1.f, Sc = 0.f;
    #pragma unroll
    for (int i = 0; i < 16; ++i) {
        int c = seg * 16 + i;
        float w = exp2f(a2 * sdt[(b * NC + c) * 512 + d]);
        float s = S[((b * NC + c) * 16 + n) * 512 + d];
        Sc = w * Sc + s;
        Wc *= w;
    }
    int o = ((b * 16 + n) * 8 + seg) * 512 + d;
    Wsg[o] = Wc;
    Ssg[o] = Sc;
}

// ---------------- comb phase C (fused prefix): hinit in place in S ---------
__global__ __launch_bounds__(512) void k_combC(float* S,
                                               const float* __restrict__ sdt,
                                               const float* __restrict__ A_log,
                                               const float* __restrict__ Wsg,
                                               const float* __restrict__ Ssg) {
    int bi = blockIdx.x;
    int b = bi >> 7, n = (bi >> 3) & 15, seg = bi & 7;
    int d = threadIdx.x;
    float a2 = -expf(A_log[d * 16 + n]) * LOG2E;
    float h = 0.f;
    int o0 = ((b * 16 + n) * 8) * 512 + d;
    for (int s = 0; s < seg; ++s)
        h = Wsg[o0 + s * 512] * h + Ssg[o0 + s * 512];
    #pragma unroll
    for (int i = 0; i < 16; ++i) {
        int c = seg * 16 + i;
        int si = ((b * NC + c) * 16 + n) * 512 + d;
        float w = exp2f(a2 * sdt[(b * NC + c) * 512 + d]);
        float sval = S[si];
        S[si] = h;
        h = w * h + sval;
    }
}

// ---------------- scan phase C: replay + skip + SiLU gate -> bf16 ----------
__global__ __launch_bounds__(512) void k_scanC(const ushort_t* __restrict__ dtp,
                                               const ushort_t* __restrict__ xcb,
                                               const float* __restrict__ Bm,
                                               const float* __restrict__ Cm,
                                               const float* __restrict__ A_log,
                                               const float* __restrict__ hinit,
                                               const float* __restrict__ Dskip,
                                               const ushort_t* __restrict__ zb,
                                               ushort_t* __restrict__ yact) {
    int b = blockIdx.x >> 7;
    int ch = blockIdx.x & 127;
    int d = threadIdx.x;
    __shared__ float Bb[CT][16], Cb[CT][16];
    {
        int t = threadIdx.x >> 4, n = threadIdx.x & 15;
        int li = ((b << 12) + ch * CT + t) * 16 + n;
        Bb[t][n] = Bm[li];
        Cb[t][n] = Cm[li];
    }
    __syncthreads();
    float a2[16], h[16];
    #pragma unroll
    for (int n = 0; n < 16; ++n) a2[n] = -expf(A_log[d * 16 + n]) * LOG2E;
    int hi = ((b * NC + ch) * 16) * 512 + d;
    #pragma unroll
    for (int n = 0; n < 16; ++n) h[n] = hinit[hi + n * 512];
    float Dsk = Dskip[d];
    int base = ((b << 12) + ch * CT) * 512 + d;
    for (int t = 0; t < CT; ++t) {
        float dv = bf2f(dtp[base + t * 512]);
        float xv = bf2f(xcb[base + t * 512]);
        float zv = bf2f(zb[base + t * 512]);
        float dx = dv * xv;
        float y = 0.f;
        #pragma unroll
        for (int n = 0; n < 16; ++n) {
            float w = exp2f(dv * a2[n]);
            h[n] = w * h[n] + dx * Bb[t][n];
            y += h[n] * Cb[t][n];
        }
        y += xv * Dsk;
        float sig = 1.f / (1.f + expf(-zv));
        yact[base + t * 512] = f2bf(y * zv * sig);
    }
}

// ---------------- GEMM3 (MFMA bf16): out = yact @ W_out, transposed store --
__global__ __launch_bounds__(256) void k_gemm3(const ushort_t* __restrict__ Abf,
                                               const ushort_t* __restrict__ Wt3,
                                               float* __restrict__ out) {
    __shared__ ushort_t As[128][40];
    __shared__ ushort_t Bs[64][40];
    __shared__ float T[64][132];
    int tid = threadIdx.x;
    int m0 = blockIdx.x * 128;
    int n0 = blockIdx.y * 64;
    int lane = tid & 63, w = tid >> 6;
    int wr = w >> 1, wc = w & 1;
    int quad = lane >> 4, lm = lane & 15;
    f32x4 acc[4][2] = {};
    for (int k0 = 0; k0 < 512; k0 += 32) {
        #pragma unroll
        for (int i = 0; i < 2; ++i) {
            int c = i * 256 + tid;
            int r = c >> 2, kq = c & 3;
            *(uint4*)&As[r][kq * 8] = *(const uint4*)&Abf[(m0 + r) * 512 + k0 + kq * 8];
        }
        {
            int r = tid >> 2, kq = tid & 3;
            *(uint4*)&Bs[r][kq * 8] = *(const uint4*)&Wt3[(n0 + r) * 512 + k0 + kq * 8];
        }
        __syncthreads();
        s16x8 af[4], bf_[2];
        #pragma unroll
        for (int mi = 0; mi < 4; ++mi)
            af[mi] = *(const s16x8*)&As[wr * 64 + mi * 16 + lm][quad * 8];
        #pragma unroll
        for (int ni = 0; ni < 2; ++ni)
            bf_[ni] = *(const s16x8*)&Bs[wc * 32 + ni * 16 + lm][quad * 8];
        #pragma unroll
        for (int mi = 0; mi < 4; ++mi)
            #pragma unroll
            for (int ni = 0; ni < 2; ++ni)
                acc[mi][ni] = __builtin_amdgcn_mfma_f32_16x16x32_bf16(
                    af[mi], bf_[ni], acc[mi][ni], 0, 0, 0);
        __syncthreads();
    }
    #pragma unroll
    for (int mi = 0; mi < 4; ++mi)
        #pragma unroll
        for (int ni = 0; ni < 2; ++ni)
            #pragma unroll
            for (int r = 0; r < 4; ++r)
                T[wc * 32 + ni * 16 + lm][wr * 64 + mi * 16 + quad * 4 + r] = acc[mi][ni][r];
    __syncthreads();
    int b = m0 >> 12;
    int l0 = m0 & 4095;
    #pragma unroll
    for (int i = 0; i < 8; ++i) {
        int f = i * 256 + tid;
        int col = f >> 5, lq = f & 31;
        float4 v = *(float4*)&T[col][lq * 4];
        *(float4*)(out + b * (256 * 4096) + (n0 + col) * 4096 + l0 + lq * 4) = v;
    }
}

extern "C" void kernel_launch(void* const* d_in, const int* in_sizes, int n_in,
                              void* d_out, int out_size, void* d_ws, size_t ws_size,
                              hipStream_t stream) {
    const float* x      = (const float*)d_in[0];
    const float* ln_g   = (const float*)d_in[1];
    const float* ln_b   = (const float*)d_in[2];
    const float* W_in   = (const float*)d_in[3];
    const float* conv_w = (const float*)d_in[4];
    const float* conv_b = (const float*)d_in[5];
    const float* W_x    = (const float*)d_in[6];
    const float* W_dt   = (const float*)d_in[7];
    const float* b_dt   = (const float*)d_in[8];
    const float* A_log  = (const float*)d_in[9];
    const float* D_skip = (const float*)d_in[10];
    const float* W_out  = (const float*)d_in[11];
    float* out = (float*)d_out;

    float* ws = (float*)d_ws;
    float* Bm   = ws;                      // 131,072 f
    float* Cm   = Bm + 131072;             // 131,072 f
    float* Sst  = Cm + 131072;             // 2,097,152 f (hinit in place)
    float* sdt  = Sst + 2097152;           // 131,072 f
    float* Wsg  = sdt + 131072;            // 131,072 f
    float* Ssg  = Wsg + 131072;            // 131,072 f
    float* dtr  = Ssg + 131072;            // 131,072 f
    ushort_t* xs_bf = (ushort_t*)(dtr + 131072);   // 2,097,152 us
    ushort_t* Wt1  = xs_bf + 2097152;      // 262,144 us
    ushort_t* Wt3  = Wt1 + 262144;         // 131,072 us
    ushort_t* Wxt  = Wt3 + 131072;         // 24,576 us (pad to 32,768)
    ushort_t* xinb = Wxt + 32768;          // 4,194,304 us
    ushort_t* zb   = xinb + 4194304;       // 4,194,304 us
    ushort_t* xcb  = zb + 4194304;         // 4,194,304 us
    ushort_t* dtp  = xcb + 4194304;        // 4,194,304 us
    ushort_t* yact = xinb;                 // alias: xinb dead after conv

    k_prep  <<<dim3(736),   dim3(256), 0, stream>>>(x, ln_g, ln_b, W_in, W_out, W_x,
                                                    xs_bf, Wt1, Wt3, Wxt);
    k_gemm1 <<<dim3(64, 8), dim3(256), 0, stream>>>(xs_bf, Wt1, xinb, zb);
    k_conv  <<<dim3(16384), dim3(256), 0, stream>>>(xinb, conv_w, conv_b, xcb);
    k_xproj1<<<dim3(128),   dim3(256), 0, stream>>>(xcb, Wxt, dtr, Bm, Cm);
    k_dtproj<<<dim3(512),   dim3(256), 0, stream>>>(dtr, W_dt, b_dt, dtp);
    k_scanA <<<dim3(256),   dim3(512), 0, stream>>>(dtp, xcb, Bm, A_log, Sst, sdt);
    k_combA <<<dim3(256),   dim3(512), 0, stream>>>(Sst, sdt, A_log, Wsg, Ssg);
    k_combC <<<dim3(256),   dim3(512), 0, stream>>>(Sst, sdt, A_log, Wsg, Ssg);
    k_scanC <<<dim3(256),   dim3(512), 0, stream>>>(dtp, xcb, Bm, Cm, A_log, Sst,
                                                    D_skip, zb, yact);
    k_gemm3 <<<dim3(64, 4), dim3(256), 0, stream>>>(yact, Wt3, out);
}

// Round 7
// 216.100 us; speedup vs baseline: 1.1769x; 1.0577x over previous
//
#include <hip/hip_runtime.h>
#include <math.h>

#define BSZ 2
#define CDIM 256
#define LSEQ 4096
#define DIN 512
#define NST 16
#define NC 128
#define CT 32
#define LOG2E 1.44269504088896f

typedef unsigned short ushort_t;
typedef short s16x8 __attribute__((ext_vector_type(8)));
typedef float f32x4 __attribute__((ext_vector_type(4)));

__device__ inline ushort_t f2bf(float f) {
    union { float f; unsigned u; } v; v.f = f;
    unsigned r = v.u + 0x7FFF + ((v.u >> 16) & 1);
    return (ushort_t)(r >> 16);
}
__device__ inline float bf2f(ushort_t u) {
    union { unsigned u; float f; } v; v.u = ((unsigned)u) << 16;
    return v.f;
}

// ---------------- prep + layernorm in one kernel ----------------
__device__ inline void tile_tr(const float* __restrict__ src, ushort_t* __restrict__ dst,
                               int R, int C, int c0, int r0, int tid) {
    __shared__ float T[32][33];
    int tx = tid & 31, ty = tid >> 5;
    #pragma unroll
    for (int i = 0; i < 4; ++i)
        T[ty + i * 8][tx] = src[(r0 + ty + i * 8) * C + c0 + tx];
    __syncthreads();
    #pragma unroll
    for (int i = 0; i < 4; ++i)
        dst[(c0 + ty + i * 8) * R + r0 + tx] = f2bf(T[tx][ty + i * 8]);
}

__global__ __launch_bounds__(256) void k_prep(const float* __restrict__ x,
                                              const float* __restrict__ g,
                                              const float* __restrict__ beta,
                                              const float* __restrict__ W_in,
                                              const float* __restrict__ W_out,
                                              const float* __restrict__ W_x,
                                              ushort_t* __restrict__ xsb,
                                              ushort_t* __restrict__ Wt1,
                                              ushort_t* __restrict__ Wt3,
                                              ushort_t* __restrict__ Wxt) {
    int bi = blockIdx.x, tid = threadIdx.x;
    if (bi >= 256) {
        if (bi < 512) {
            int rem = bi - 256;
            tile_tr(W_in, Wt1, 256, 1024, (rem & 31) * 32, (rem >> 5) * 32, tid);
        } else if (bi < 640) {
            int rem = bi - 512;
            tile_tr(W_out, Wt3, 512, 256, (rem & 7) * 32, (rem >> 3) * 32, tid);
        } else {
            int f = (bi - 640) * 256 + tid;
            int n = f >> 9, dcol = f & 511;
            Wxt[n * 512 + dcol] = f2bf(W_x[dcol * 48 + n]);
        }
        return;
    }
    int b  = bi >> 7;
    int l0 = (bi & 127) * 32;
    __shared__ float T[256][33];
    __shared__ float ps[8][32], ps2[8][32];
    __shared__ float mus[32], rs[32];
    #pragma unroll
    for (int i = 0; i < 8; ++i) {
        int f = i * 256 + tid;
        int c = f >> 3, lq = f & 7;
        float4 v = *(const float4*)(x + (b * 256 + c) * 4096 + l0 + lq * 4);
        T[c][lq * 4 + 0] = v.x; T[c][lq * 4 + 1] = v.y;
        T[c][lq * 4 + 2] = v.z; T[c][lq * 4 + 3] = v.w;
    }
    __syncthreads();
    {
        int lt = tid & 31, q = tid >> 5;
        float s = 0.f, s2 = 0.f;
        #pragma unroll
        for (int c = q * 32; c < q * 32 + 32; ++c) {
            float v = T[c][lt];
            s += v; s2 += v * v;
        }
        ps[q][lt] = s; ps2[q][lt] = s2;
    }
    __syncthreads();
    if (tid < 32) {
        float ts = 0.f, ts2 = 0.f;
        #pragma unroll
        for (int q = 0; q < 8; ++q) { ts += ps[q][tid]; ts2 += ps2[q][tid]; }
        float mu  = ts * (1.f / 256.f);
        float var = ts2 * (1.f / 256.f) - mu * mu;
        mus[tid] = mu;
        rs[tid]  = rsqrtf(var + 1e-5f);
    }
    __syncthreads();
    float gg = g[tid], bb = beta[tid];
    #pragma unroll
    for (int i = 0; i < 32; ++i) {
        float v = (T[tid][i] - mus[i]) * rs[i] * gg + bb;
        xsb[(b * 4096 + l0 + i) * 256 + tid] = f2bf(v);
    }
}

// ---------------- GEMM1 (MFMA bf16): xz = xs @ W_in -> bf16 xin,z ----------
__global__ __launch_bounds__(256) void k_gemm1(const ushort_t* __restrict__ Abf,
                                               const ushort_t* __restrict__ Wt,
                                               ushort_t* __restrict__ xinb,
                                               ushort_t* __restrict__ zb) {
    __shared__ ushort_t As[128][40];
    __shared__ ushort_t Bs[128][40];
    int tid = threadIdx.x;
    int m0 = blockIdx.x * 128;
    int n0 = blockIdx.y * 128;
    int lane = tid & 63, w = tid >> 6;
    int wr = w >> 1, wc = w & 1;
    int quad = lane >> 4, lm = lane & 15;
    f32x4 acc[4][4] = {};
    for (int k0 = 0; k0 < 256; k0 += 32) {
        #pragma unroll
        for (int i = 0; i < 2; ++i) {
            int c = i * 256 + tid;
            int r = c >> 2, kq = c & 3;
            *(uint4*)&As[r][kq * 8] = *(const uint4*)&Abf[(m0 + r) * 256 + k0 + kq * 8];
            *(uint4*)&Bs[r][kq * 8] = *(const uint4*)&Wt[(n0 + r) * 256 + k0 + kq * 8];
        }
        __syncthreads();
        s16x8 af[4], bf_[4];
        #pragma unroll
        for (int mi = 0; mi < 4; ++mi)
            af[mi] = *(const s16x8*)&As[wr * 64 + mi * 16 + lm][quad * 8];
        #pragma unroll
        for (int ni = 0; ni < 4; ++ni)
            bf_[ni] = *(const s16x8*)&Bs[wc * 64 + ni * 16 + lm][quad * 8];
        #pragma unroll
        for (int mi = 0; mi < 4; ++mi)
            #pragma unroll
            for (int ni = 0; ni < 4; ++ni)
                acc[mi][ni] = __builtin_amdgcn_mfma_f32_16x16x32_bf16(
                    af[mi], bf_[ni], acc[mi][ni], 0, 0, 0);
        __syncthreads();
    }
    bool isz = (n0 >= 512);
    ushort_t* out = isz ? zb : xinb;
    int nb = isz ? n0 - 512 : n0;
    #pragma unroll
    for (int mi = 0; mi < 4; ++mi) {
        #pragma unroll
        for (int ni = 0; ni < 4; ++ni) {
            int colg = nb + wc * 64 + ni * 16 + lm;
            #pragma unroll
            for (int r = 0; r < 4; ++r) {
                int rowg = m0 + wr * 64 + mi * 16 + quad * 4 + r;
                out[rowg * 512 + colg] = f2bf(acc[mi][ni][r]);
            }
        }
    }
}

// ---------------- depthwise causal conv(4) + SiLU -> bf16 xcb --------------
__global__ __launch_bounds__(256) void k_conv(const ushort_t* __restrict__ xinb,
                                              const float* __restrict__ cw,
                                              const float* __restrict__ cb,
                                              ushort_t* __restrict__ xcb) {
    int idx = blockIdx.x * 256 + threadIdx.x;
    int d = idx & 511;
    int r = idx >> 9;
    int l = r & 4095;
    int b = r >> 12;
    float s = cb[d];
    #pragma unroll
    for (int k = 0; k < 4; ++k) {
        int ll = l - 3 + k;
        if (ll >= 0) s += cw[d * 4 + k] * bf2f(xinb[(((b << 12) + ll) << 9) + d]);
    }
    float sig = 1.f / (1.f + expf(-s));
    xcb[idx] = f2bf(s * sig);
}

// ---------------- x-proj (MFMA): dbl = xc @ W_x -> dtr/Bm/Cm ---------------
__global__ __launch_bounds__(256) void k_xproj1(const ushort_t* __restrict__ xcb,
                                                const ushort_t* __restrict__ Wxt,
                                                float* __restrict__ dtr,
                                                float* __restrict__ Bm,
                                                float* __restrict__ Cm) {
    __shared__ ushort_t As[64][72];
    __shared__ ushort_t Bs[48][72];
    int tid = threadIdx.x;
    int m0 = blockIdx.x * 64;
    int lane = tid & 63, w = tid >> 6;
    int quad = lane >> 4, lm = lane & 15;
    f32x4 acc[3] = {};
    for (int k0 = 0; k0 < 512; k0 += 64) {
        #pragma unroll
        for (int i = 0; i < 2; ++i) {
            int f = i * 256 + tid;
            int r = f >> 3, kq = f & 7;
            *(uint4*)&As[r][kq * 8] = *(const uint4*)&xcb[(m0 + r) * 512 + k0 + kq * 8];
        }
        if (tid < 192) {
            #pragma unroll
            for (int i = 0; i < 2; ++i) {
                int f = i * 192 + tid;
                int r = f >> 3, kq = f & 7;
                *(uint4*)&Bs[r][kq * 8] = *(const uint4*)&Wxt[r * 512 + k0 + kq * 8];
            }
        }
        __syncthreads();
        #pragma unroll
        for (int kk = 0; kk < 2; ++kk) {
            s16x8 af = *(const s16x8*)&As[w * 16 + lm][kk * 32 + quad * 8];
            #pragma unroll
            for (int nt = 0; nt < 3; ++nt) {
                s16x8 bv = *(const s16x8*)&Bs[nt * 16 + lm][kk * 32 + quad * 8];
                acc[nt] = __builtin_amdgcn_mfma_f32_16x16x32_bf16(af, bv, acc[nt], 0, 0, 0);
            }
        }
        __syncthreads();
    }
    #pragma unroll
    for (int nt = 0; nt < 3; ++nt) {
        float* dst = (nt == 0) ? dtr : ((nt == 1) ? Bm : Cm);
        #pragma unroll
        for (int r = 0; r < 4; ++r) {
            int row = m0 + w * 16 + quad * 4 + r;
            dst[row * 16 + lm] = acc[nt][r];
        }
    }
}

// ---------------- dt-proj: dtp = softplus(dtr @ W_dt + b_dt) -> bf16 -------
__global__ __launch_bounds__(256) void k_dtproj(const float* __restrict__ dtr,
                                                const float* __restrict__ Wdt,
                                                const float* __restrict__ bdt,
                                                ushort_t* __restrict__ dtp) {
    int tid = threadIdx.x;
    int t0 = blockIdx.x * 16;
    __shared__ float R[16][17];
    float w0[16], w1[16];
    #pragma unroll
    for (int r = 0; r < 16; ++r) {
        w0[r] = Wdt[r * 512 + tid];
        w1[r] = Wdt[r * 512 + 256 + tid];
    }
    float b0 = bdt[tid], b1 = bdt[256 + tid];
    {
        int t = tid >> 4, r = tid & 15;
        R[t][r] = dtr[(t0 + t) * 16 + r];
    }
    __syncthreads();
    for (int t = 0; t < 16; ++t) {
        float s0 = b0, s1 = b1;
        #pragma unroll
        for (int r = 0; r < 16; ++r) {
            float dv = R[t][r];
            s0 += dv * w0[r];
            s1 += dv * w1[r];
        }
        s0 = (s0 > 20.f) ? s0 : log1pf(expf(s0));
        s1 = (s1 > 20.f) ? s1 : log1pf(expf(s1));
        dtp[(t0 + t) * 512 + tid] = f2bf(s0);
        dtp[(t0 + t) * 512 + 256 + tid] = f2bf(s1);
    }
}

// ---------------- scan phase A: register-staged loads ----------------
__global__ __launch_bounds__(512) void k_scanA(const ushort_t* __restrict__ dtp,
                                               const ushort_t* __restrict__ xcb,
                                               const float* __restrict__ Bm,
                                               const float* __restrict__ A_log,
                                               float* __restrict__ S,
                                               float* __restrict__ sdt) {
    int b = blockIdx.x >> 7;
    int ch = blockIdx.x & 127;
    int d = threadIdx.x;
    __shared__ float Bb[CT][16];
    {
        int t = threadIdx.x >> 4, n = threadIdx.x & 15;
        Bb[t][n] = Bm[((b << 12) + ch * CT + t) * 16 + n];
    }
    __syncthreads();
    int base = ((b << 12) + ch * CT) * 512 + d;
    // stage all timesteps: independent loads, one latency
    float dv_[CT], xv_[CT];
    #pragma unroll
    for (int t = 0; t < CT; ++t) {
        dv_[t] = bf2f(dtp[base + t * 512]);
        xv_[t] = bf2f(xcb[base + t * 512]);
    }
    float a2[16];
    #pragma unroll
    for (int n = 0; n < 16; ++n) a2[n] = -expf(A_log[d * 16 + n]) * LOG2E;
    float h[16] = {};
    float sum_dt = 0.f;
    #pragma unroll
    for (int t = 0; t < CT; ++t) {
        float dv = dv_[t];
        float dx = dv * xv_[t];
        sum_dt += dv;
        #pragma unroll
        for (int n = 0; n < 16; ++n) {
            float w = exp2f(dv * a2[n]);
            h[n] = w * h[n] + dx * Bb[t][n];
        }
    }
    int so = ((b * NC + ch) * 16) * 512 + d;
    #pragma unroll
    for (int n = 0; n < 16; ++n)
        S[so + n * 512] = h[n];
    sdt[(b * NC + ch) * 512 + d] = sum_dt;
}

// ---------------- comb phase A: per-segment compose (16 chunks) ------------
__global__ __launch_bounds__(512) void k_combA(const float* __restrict__ S,
                                               const float* __restrict__ sdt,
                                               const float* __restrict__ A_log,
                                               float* __restrict__ Wsg,
                                               float* __restrict__ Ssg) {
    int bi = blockIdx.x;
    int b = bi >> 7, n = (bi >> 3) & 15, seg = bi & 7;
    int d = threadIdx.x;
    float a2 = -expf(A_log[d * 16 + n]) * LOG2E;
    float sv_[16], wv_[16];
    #pragma unroll
    for (int i = 0; i < 16; ++i) {
        int c = seg * 16 + i;
        wv_[i] = exp2f(a2 * sdt[(b * NC + c) * 512 + d]);
        sv_[i] = S[((b * NC + c) * 16 + n) * 512 + d];
    }
    float Wc = 1.f, Sc = 0.f;
    #pragma unroll
    for (int i = 0; i < 16; ++i) {
        Sc = wv_[i] * Sc + sv_[i];
        Wc *= wv_[i];
    }
    int o = ((b * 16 + n) * 8 + seg) * 512 + d;
    Wsg[o] = Wc;
    Ssg[o] = Sc;
}

// ---------------- comb phase C: explicit load->compute->store phases -------
__global__ __launch_bounds__(512) void k_combC(float* S,
                                               const float* __restrict__ sdt,
                                               const float* __restrict__ A_log,
                                               const float* __restrict__ Wsg,
                                               const float* __restrict__ Ssg) {
    int bi = blockIdx.x;
    int b = bi >> 7, n = (bi >> 3) & 15, seg = bi & 7;
    int d = threadIdx.x;
    float a2 = -expf(A_log[d * 16 + n]) * LOG2E;
    // preload segment-local chunk states + weights (independent of h)
    float sval[16], wv[16];
    #pragma unroll
    for (int i = 0; i < 16; ++i) {
        int c = seg * 16 + i;
        sval[i] = S[((b * NC + c) * 16 + n) * 512 + d];
        wv[i]   = exp2f(a2 * sdt[(b * NC + c) * 512 + d]);
    }
    // segment prefix (<=7 L2-hot dependent loads)
    float h = 0.f;
    int o0 = ((b * 16 + n) * 8) * 512 + d;
    for (int s = 0; s < seg; ++s)
        h = Wsg[o0 + s * 512] * h + Ssg[o0 + s * 512];
    #pragma unroll
    for (int i = 0; i < 16; ++i) {
        int c = seg * 16 + i;
        S[((b * NC + c) * 16 + n) * 512 + d] = h;
        h = wv[i] * h + sval[i];
    }
}

// ---------------- scan phase C: register-staged loads ----------------
__global__ __launch_bounds__(512) void k_scanC(const ushort_t* __restrict__ dtp,
                                               const ushort_t* __restrict__ xcb,
                                               const float* __restrict__ Bm,
                                               const float* __restrict__ Cm,
                                               const float* __restrict__ A_log,
                                               const float* __restrict__ hinit,
                                               const float* __restrict__ Dskip,
                                               const ushort_t* __restrict__ zb,
                                               ushort_t* __restrict__ yact) {
    int b = blockIdx.x >> 7;
    int ch = blockIdx.x & 127;
    int d = threadIdx.x;
    __shared__ float Bb[CT][16], Cb[CT][16];
    {
        int t = threadIdx.x >> 4, n = threadIdx.x & 15;
        int li = ((b << 12) + ch * CT + t) * 16 + n;
        Bb[t][n] = Bm[li];
        Cb[t][n] = Cm[li];
    }
    __syncthreads();
    int base = ((b << 12) + ch * CT) * 512 + d;
    float dv_[CT], xv_[CT], zv_[CT];
    #pragma unroll
    for (int t = 0; t < CT; ++t) {
        dv_[t] = bf2f(dtp[base + t * 512]);
        xv_[t] = bf2f(xcb[base + t * 512]);
        zv_[t] = bf2f(zb[base + t * 512]);
    }
    float a2[16], h[16];
    #pragma unroll
    for (int n = 0; n < 16; ++n) a2[n] = -expf(A_log[d * 16 + n]) * LOG2E;
    int hi = ((b * NC + ch) * 16) * 512 + d;
    #pragma unroll
    for (int n = 0; n < 16; ++n) h[n] = hinit[hi + n * 512];
    float Dsk = Dskip[d];
    #pragma unroll
    for (int t = 0; t < CT; ++t) {
        float dv = dv_[t];
        float xv = xv_[t];
        float zv = zv_[t];
        float dx = dv * xv;
        float y = 0.f;
        #pragma unroll
        for (int n = 0; n < 16; ++n) {
            float w = exp2f(dv * a2[n]);
            h[n] = w * h[n] + dx * Bb[t][n];
            y += h[n] * Cb[t][n];
        }
        y += xv * Dsk;
        float sig = 1.f / (1.f + expf(-zv));
        yact[base + t * 512] = f2bf(y * zv * sig);
    }
}

// ---------------- GEMM3 (MFMA bf16): out = yact @ W_out, transposed store --
__global__ __launch_bounds__(256) void k_gemm3(const ushort_t* __restrict__ Abf,
                                               const ushort_t* __restrict__ Wt3,
                                               float* __restrict__ out) {
    __shared__ ushort_t As[128][40];
    __shared__ ushort_t Bs[64][40];
    __shared__ float T[64][132];
    int tid = threadIdx.x;
    int m0 = blockIdx.x * 128;
    int n0 = blockIdx.y * 64;
    int lane = tid & 63, w = tid >> 6;
    int wr = w >> 1, wc = w & 1;
    int quad = lane >> 4, lm = lane & 15;
    f32x4 acc[4][2] = {};
    for (int k0 = 0; k0 < 512; k0 += 32) {
        #pragma unroll
        for (int i = 0; i < 2; ++i) {
            int c = i * 256 + tid;
            int r = c >> 2, kq = c & 3;
            *(uint4*)&As[r][kq * 8] = *(const uint4*)&Abf[(m0 + r) * 512 + k0 + kq * 8];
        }
        {
            int r = tid >> 2, kq = tid & 3;
            *(uint4*)&Bs[r][kq * 8] = *(const uint4*)&Wt3[(n0 + r) * 512 + k0 + kq * 8];
        }
        __syncthreads();
        s16x8 af[4], bf_[2];
        #pragma unroll
        for (int mi = 0; mi < 4; ++mi)
            af[mi] = *(const s16x8*)&As[wr * 64 + mi * 16 + lm][quad * 8];
        #pragma unroll
        for (int ni = 0; ni < 2; ++ni)
            bf_[ni] = *(const s16x8*)&Bs[wc * 32 + ni * 16 + lm][quad * 8];
        #pragma unroll
        for (int mi = 0; mi < 4; ++mi)
            #pragma unroll
            for (int ni = 0; ni < 2; ++ni)
                acc[mi][ni] = __builtin_amdgcn_mfma_f32_16x16x32_bf16(
                    af[mi], bf_[ni], acc[mi][ni], 0, 0, 0);
        __syncthreads();
    }
    #pragma unroll
    for (int mi = 0; mi < 4; ++mi)
        #pragma unroll
        for (int ni = 0; ni < 2; ++ni)
            #pragma unroll
            for (int r = 0; r < 4; ++r)
                T[wc * 32 + ni * 16 + lm][wr * 64 + mi * 16 + quad * 4 + r] = acc[mi][ni][r];
    __syncthreads();
    int b = m0 >> 12;
    int l0 = m0 & 4095;
    #pragma unroll
    for (int i = 0; i < 8; ++i) {
        int f = i * 256 + tid;
        int col = f >> 5, lq = f & 31;
        float4 v = *(float4*)&T[col][lq * 4];
        *(float4*)(out + b * (256 * 4096) + (n0 + col) * 4096 + l0 + lq * 4) = v;
    }
}

extern "C" void kernel_launch(void* const* d_in, const int* in_sizes, int n_in,
                              void* d_out, int out_size, void* d_ws, size_t ws_size,
                              hipStream_t stream) {
    const float* x      = (const float*)d_in[0];
    const float* ln_g   = (const float*)d_in[1];
    const float* ln_b   = (const float*)d_in[2];
    const float* W_in   = (const float*)d_in[3];
    const float* conv_w = (const float*)d_in[4];
    const float* conv_b = (const float*)d_in[5];
    const float* W_x    = (const float*)d_in[6];
    const float* W_dt   = (const float*)d_in[7];
    const float* b_dt   = (const float*)d_in[8];
    const float* A_log  = (const float*)d_in[9];
    const float* D_skip = (const float*)d_in[10];
    const float* W_out  = (const float*)d_in[11];
    float* out = (float*)d_out;

    float* ws = (float*)d_ws;
    float* Bm   = ws;                      // 131,072 f
    float* Cm   = Bm + 131072;             // 131,072 f
    float* Sst  = Cm + 131072;             // 2,097,152 f (hinit in place)
    float* sdt  = Sst + 2097152;           // 131,072 f
    float* Wsg  = sdt + 131072;            // 131,072 f
    float* Ssg  = Wsg + 131072;            // 131,072 f
    float* dtr  = Ssg + 131072;            // 131,072 f
    ushort_t* xs_bf = (ushort_t*)(dtr + 131072);   // 2,097,152 us
    ushort_t* Wt1  = xs_bf + 2097152;      // 262,144 us
    ushort_t* Wt3  = Wt1 + 262144;         // 131,072 us
    ushort_t* Wxt  = Wt3 + 131072;         // 24,576 us (pad to 32,768)
    ushort_t* xinb = Wxt + 32768;          // 4,194,304 us
    ushort_t* zb   = xinb + 4194304;       // 4,194,304 us
    ushort_t* xcb  = zb + 4194304;         // 4,194,304 us
    ushort_t* dtp  = xcb + 4194304;        // 4,194,304 us
    ushort_t* yact = xinb;                 // alias: xinb dead after conv

    k_prep  <<<dim3(736),   dim3(256), 0, stream>>>(x, ln_g, ln_b, W_in, W_out, W_x,
                                                    xs_bf, Wt1, Wt3, Wxt);
    k_gemm1 <<<dim3(64, 8), dim3(256), 0, stream>>>(xs_bf, Wt1, xinb, zb);
    k_conv  <<<dim3(16384), dim3(256), 0, stream>>>(xinb, conv_w, conv_b, xcb);
    k_xproj1<<<dim3(128),   dim3(256), 0, stream>>>(xcb, Wxt, dtr, Bm, Cm);
    k_dtproj<<<dim3(512),   dim3(256), 0, stream>>>(dtr, W_dt, b_dt, dtp);
    k_scanA <<<dim3(256),   dim3(512), 0, stream>>>(dtp, xcb, Bm, A_log, Sst, sdt);
    k_combA <<<dim3(256),   dim3(512), 0, stream>>>(Sst, sdt, A_log, Wsg, Ssg);
    k_combC <<<dim3(256),   dim3(512), 0, stream>>>(Sst, sdt, A_log, Wsg, Ssg);
    k_scanC <<<dim3(256),   dim3(512), 0, stream>>>(dtp, xcb, Bm, Cm, A_log, Sst,
                                                    D_skip, zb, yact);
    k_gemm3 <<<dim3(64, 4), dim3(256), 0, stream>>>(yact, Wt3, out);
}

// Round 8
// 199.429 us; speedup vs baseline: 1.2752x; 1.0836x over previous
//
#include <hip/hip_runtime.h>
#include <math.h>

#define BSZ 2
#define CDIM 256
#define LSEQ 4096
#define DIN 512
#define NST 16
#define NC 256          // scan chunks per batch (CT=16)
#define CT 16
#define LOG2E 1.44269504088896f

typedef unsigned short ushort_t;
typedef short s16x8 __attribute__((ext_vector_type(8)));
typedef float f32x4 __attribute__((ext_vector_type(4)));

__device__ inline ushort_t f2bf(float f) {
    union { float f; unsigned u; } v; v.f = f;
    unsigned r = v.u + 0x7FFF + ((v.u >> 16) & 1);
    return (ushort_t)(r >> 16);
}
__device__ inline float bf2f(ushort_t u) {
    union { unsigned u; float f; } v; v.u = ((unsigned)u) << 16;
    return v.f;
}

// ---------------- prep + layernorm in one kernel ----------------
__device__ inline void tile_tr(const float* __restrict__ src, ushort_t* __restrict__ dst,
                               int R, int C, int c0, int r0, int tid) {
    __shared__ float T[32][33];
    int tx = tid & 31, ty = tid >> 5;
    #pragma unroll
    for (int i = 0; i < 4; ++i)
        T[ty + i * 8][tx] = src[(r0 + ty + i * 8) * C + c0 + tx];
    __syncthreads();
    #pragma unroll
    for (int i = 0; i < 4; ++i)
        dst[(c0 + ty + i * 8) * R + r0 + tx] = f2bf(T[tx][ty + i * 8]);
}

__global__ __launch_bounds__(256) void k_prep(const float* __restrict__ x,
                                              const float* __restrict__ g,
                                              const float* __restrict__ beta,
                                              const float* __restrict__ W_in,
                                              const float* __restrict__ W_out,
                                              const float* __restrict__ W_x,
                                              ushort_t* __restrict__ xsb,
                                              ushort_t* __restrict__ Wt1,
                                              ushort_t* __restrict__ Wt3,
                                              ushort_t* __restrict__ Wxt) {
    int bi = blockIdx.x, tid = threadIdx.x;
    if (bi >= 256) {
        if (bi < 512) {
            int rem = bi - 256;
            tile_tr(W_in, Wt1, 256, 1024, (rem & 31) * 32, (rem >> 5) * 32, tid);
        } else if (bi < 640) {
            int rem = bi - 512;
            tile_tr(W_out, Wt3, 512, 256, (rem & 7) * 32, (rem >> 3) * 32, tid);
        } else {
            int f = (bi - 640) * 256 + tid;
            int n = f >> 9, dcol = f & 511;
            Wxt[n * 512 + dcol] = f2bf(W_x[dcol * 48 + n]);
        }
        return;
    }
    int b  = bi >> 7;
    int l0 = (bi & 127) * 32;
    __shared__ float T[256][33];
    __shared__ float ps[8][32], ps2[8][32];
    __shared__ float mus[32], rs[32];
    #pragma unroll
    for (int i = 0; i < 8; ++i) {
        int f = i * 256 + tid;
        int c = f >> 3, lq = f & 7;
        float4 v = *(const float4*)(x + (b * 256 + c) * 4096 + l0 + lq * 4);
        T[c][lq * 4 + 0] = v.x; T[c][lq * 4 + 1] = v.y;
        T[c][lq * 4 + 2] = v.z; T[c][lq * 4 + 3] = v.w;
    }
    __syncthreads();
    {
        int lt = tid & 31, q = tid >> 5;
        float s = 0.f, s2 = 0.f;
        #pragma unroll
        for (int c = q * 32; c < q * 32 + 32; ++c) {
            float v = T[c][lt];
            s += v; s2 += v * v;
        }
        ps[q][lt] = s; ps2[q][lt] = s2;
    }
    __syncthreads();
    if (tid < 32) {
        float ts = 0.f, ts2 = 0.f;
        #pragma unroll
        for (int q = 0; q < 8; ++q) { ts += ps[q][tid]; ts2 += ps2[q][tid]; }
        float mu  = ts * (1.f / 256.f);
        float var = ts2 * (1.f / 256.f) - mu * mu;
        mus[tid] = mu;
        rs[tid]  = rsqrtf(var + 1e-5f);
    }
    __syncthreads();
    float gg = g[tid], bb = beta[tid];
    #pragma unroll
    for (int i = 0; i < 32; ++i) {
        float v = (T[tid][i] - mus[i]) * rs[i] * gg + bb;
        xsb[(b * 4096 + l0 + i) * 256 + tid] = f2bf(v);
    }
}

// ---------------- GEMM1 (MFMA bf16) with vectorized LDS-transpose epilogue -
__global__ __launch_bounds__(256) void k_gemm1(const ushort_t* __restrict__ Abf,
                                               const ushort_t* __restrict__ Wt,
                                               ushort_t* __restrict__ xinb,
                                               ushort_t* __restrict__ zb) {
    __shared__ ushort_t As[128][40];
    __shared__ ushort_t Bs[128][40];
    __shared__ ushort_t Ct[128][136];
    int tid = threadIdx.x;
    int m0 = blockIdx.x * 128;
    int n0 = blockIdx.y * 128;
    int lane = tid & 63, w = tid >> 6;
    int wr = w >> 1, wc = w & 1;
    int quad = lane >> 4, lm = lane & 15;
    f32x4 acc[4][4] = {};
    for (int k0 = 0; k0 < 256; k0 += 32) {
        #pragma unroll
        for (int i = 0; i < 2; ++i) {
            int c = i * 256 + tid;
            int r = c >> 2, kq = c & 3;
            *(uint4*)&As[r][kq * 8] = *(const uint4*)&Abf[(m0 + r) * 256 + k0 + kq * 8];
            *(uint4*)&Bs[r][kq * 8] = *(const uint4*)&Wt[(n0 + r) * 256 + k0 + kq * 8];
        }
        __syncthreads();
        s16x8 af[4], bf_[4];
        #pragma unroll
        for (int mi = 0; mi < 4; ++mi)
            af[mi] = *(const s16x8*)&As[wr * 64 + mi * 16 + lm][quad * 8];
        #pragma unroll
        for (int ni = 0; ni < 4; ++ni)
            bf_[ni] = *(const s16x8*)&Bs[wc * 64 + ni * 16 + lm][quad * 8];
        #pragma unroll
        for (int mi = 0; mi < 4; ++mi)
            #pragma unroll
            for (int ni = 0; ni < 4; ++ni)
                acc[mi][ni] = __builtin_amdgcn_mfma_f32_16x16x32_bf16(
                    af[mi], bf_[ni], acc[mi][ni], 0, 0, 0);
        __syncthreads();
    }
    // stage C tile as bf16 in LDS, then 16B vectorized stores
    #pragma unroll
    for (int mi = 0; mi < 4; ++mi)
        #pragma unroll
        for (int ni = 0; ni < 4; ++ni)
            #pragma unroll
            for (int r = 0; r < 4; ++r)
                Ct[wr * 64 + mi * 16 + quad * 4 + r][wc * 64 + ni * 16 + lm] =
                    f2bf(acc[mi][ni][r]);
    __syncthreads();
    bool isz = (n0 >= 512);
    ushort_t* outp = isz ? zb : xinb;
    int nb = isz ? n0 - 512 : n0;
    #pragma unroll
    for (int i = 0; i < 8; ++i) {
        int f = i * 256 + tid;          // 2048 uint4 chunks
        int row = f >> 4, q = f & 15;
        *(uint4*)&outp[(m0 + row) * 512 + nb + q * 8] = *(uint4*)&Ct[row][q * 8];
    }
}

// ---------------- MEGA: conv + x-proj MFMA + dt-proj + scanA ----------------
// grid 256 = (b, macro-chunk of 32 tokens); 512 threads (d / MFMA lanes)
__global__ __launch_bounds__(512) void k_mega(const ushort_t* __restrict__ xinb,
                                              const ushort_t* __restrict__ Wxt,
                                              const float* __restrict__ Wdt,
                                              const float* __restrict__ bdt,
                                              const float* __restrict__ A_log,
                                              const float* __restrict__ cw,
                                              const float* __restrict__ cb,
                                              ushort_t* __restrict__ xcb,
                                              ushort_t* __restrict__ dtp,
                                              float* __restrict__ Bm,
                                              float* __restrict__ Cm,
                                              float* __restrict__ S,
                                              float* __restrict__ sdt) {
    int b = blockIdx.x >> 7;
    int mc = blockIdx.x & 127;
    int l0 = mc * 32;
    int tid = threadIdx.x;
    __shared__ ushort_t xs[35][520];    // tokens l0-3 .. l0+31, padded rows
    __shared__ ushort_t Bsh[48][72];
    __shared__ float dbl[32][49];       // cols 0..15 dt-rank, 16..31 Bm
    // stage x with 3-token halo (zeros at seq start)
    for (int f = tid; f < 35 * 64; f += 512) {
        int row = f >> 6, q = f & 63;
        int tok = l0 - 3 + row;
        uint4 v = make_uint4(0u, 0u, 0u, 0u);
        if (tok >= 0) v = *(const uint4*)&xinb[(((b << 12) + tok) << 9) + q * 8];
        *(uint4*)&xs[row][q * 8] = v;
    }
    __syncthreads();
    int d = tid;
    float cw0 = cw[d * 4], cw1 = cw[d * 4 + 1], cw2 = cw[d * 4 + 2], cw3 = cw[d * 4 + 3];
    float cb0 = cb[d];
    float xr[35];
    #pragma unroll
    for (int t = 0; t < 35; ++t) xr[t] = bf2f(xs[t][d]);
    float xc[32];
    #pragma unroll
    for (int t = 0; t < 32; ++t) {
        float s = cb0 + cw0 * xr[t] + cw1 * xr[t + 1] + cw2 * xr[t + 2] + cw3 * xr[t + 3];
        float sig = 1.f / (1.f + expf(-s));
        s = s * sig;
        ushort_t uv = f2bf(s);
        xc[t] = bf2f(uv);               // keep bf16-rounded (consistent w/ scanC)
        xcb[(((b << 12) + l0 + t) << 9) + d] = uv;
    }
    __syncthreads();                    // all reads of xs done
    #pragma unroll
    for (int t = 0; t < 32; ++t) xs[t + 3][d] = f2bf(xc[t]);
    __syncthreads();
    // MFMA: dbl(32x48) = xc(32x512) @ Wxt^T ; 6 active waves: (tt,nt)
    int lane = tid & 63, w = tid >> 6;
    int quad = lane >> 4, lm = lane & 15;
    bool active = (w < 6);
    int tt = w / 3, nt = w % 3;
    f32x4 acc = {};
    for (int k0 = 0; k0 < 512; k0 += 64) {
        for (int f = tid; f < 384; f += 512) {
            int r = f >> 3, kq = f & 7;
            *(uint4*)&Bsh[r][kq * 8] = *(const uint4*)&Wxt[r * 512 + k0 + kq * 8];
        }
        __syncthreads();
        if (active) {
            #pragma unroll
            for (int kk = 0; kk < 2; ++kk) {
                s16x8 af = *(const s16x8*)&xs[3 + tt * 16 + lm][k0 + kk * 32 + quad * 8];
                s16x8 bv = *(const s16x8*)&Bsh[nt * 16 + lm][kk * 32 + quad * 8];
                acc = __builtin_amdgcn_mfma_f32_16x16x32_bf16(af, bv, acc, 0, 0, 0);
            }
        }
        __syncthreads();
    }
    if (active) {
        #pragma unroll
        for (int r = 0; r < 4; ++r) {
            int trow = tt * 16 + quad * 4 + r;
            if (nt == 0) {
                dbl[trow][lm] = acc[r];
            } else if (nt == 1) {
                dbl[trow][16 + lm] = acc[r];
                Bm[(((b << 12) + l0 + trow) << 4) + lm] = acc[r];
            } else {
                Cm[(((b << 12) + l0 + trow) << 4) + lm] = acc[r];
            }
        }
    }
    __syncthreads();
    // dt-proj for this thread's d over 32 tokens
    float wdt[16];
    #pragma unroll
    for (int r = 0; r < 16; ++r) wdt[r] = Wdt[r * 512 + d];
    float bd = bdt[d];
    float dt[32];
    #pragma unroll
    for (int t = 0; t < 32; ++t) {
        float s = bd;
        #pragma unroll
        for (int r = 0; r < 16; ++r) s += dbl[t][r] * wdt[r];
        s = (s > 20.f) ? s : log1pf(expf(s));
        ushort_t uv = f2bf(s);
        dt[t] = bf2f(uv);
        dtp[(((b << 12) + l0 + t) << 9) + d] = uv;
    }
    // scanA: two CT=16 sub-chunks
    float a2[16];
    #pragma unroll
    for (int n = 0; n < 16; ++n) a2[n] = -expf(A_log[d * 16 + n]) * LOG2E;
    #pragma unroll
    for (int sc2 = 0; sc2 < 2; ++sc2) {
        float h[16] = {};
        float sum_dt = 0.f;
        #pragma unroll
        for (int tt2 = 0; tt2 < 16; ++tt2) {
            int t = sc2 * 16 + tt2;
            float dv = dt[t];
            float dx = dv * xc[t];
            sum_dt += dv;
            #pragma unroll
            for (int n = 0; n < 16; ++n) {
                float w2 = exp2f(dv * a2[n]);
                h[n] = w2 * h[n] + dx * dbl[t][16 + n];
            }
        }
        int ch = mc * 2 + sc2;
        int so = ((b * NC + ch) * 16) * 512 + d;
        #pragma unroll
        for (int n = 0; n < 16; ++n)
            S[so + n * 512] = h[n];
        sdt[(b * NC + ch) * 512 + d] = sum_dt;
    }
}

// ---------------- comb phase A: per-segment compose (16 chunks) ------------
// grid 512 = (b, n, seg); 512 thr = d
__global__ __launch_bounds__(512) void k_combA(const float* __restrict__ S,
                                               const float* __restrict__ sdt,
                                               const float* __restrict__ A_log,
                                               float* __restrict__ Wsg,
                                               float* __restrict__ Ssg) {
    int bi = blockIdx.x;
    int b = bi >> 8, n = (bi >> 4) & 15, seg = bi & 15;
    int d = threadIdx.x;
    float a2 = -expf(A_log[d * 16 + n]) * LOG2E;
    float sv_[16], wv_[16];
    #pragma unroll
    for (int i = 0; i < 16; ++i) {
        int c = seg * 16 + i;
        wv_[i] = exp2f(a2 * sdt[(b * NC + c) * 512 + d]);
        sv_[i] = S[((b * NC + c) * 16 + n) * 512 + d];
    }
    float Wc = 1.f, Sc = 0.f;
    #pragma unroll
    for (int i = 0; i < 16; ++i) {
        Sc = wv_[i] * Sc + sv_[i];
        Wc *= wv_[i];
    }
    int o = ((b * 16 + n) * 16 + seg) * 512 + d;
    Wsg[o] = Wc;
    Ssg[o] = Sc;
}

// ---------------- comb phase C: prefix + replay, hinit in place in S -------
__global__ __launch_bounds__(512) void k_combC(float* S,
                                               const float* __restrict__ sdt,
                                               const float* __restrict__ A_log,
                                               const float* __restrict__ Wsg,
                                               const float* __restrict__ Ssg) {
    int bi = blockIdx.x;
    int b = bi >> 8, n = (bi >> 4) & 15, seg = bi & 15;
    int d = threadIdx.x;
    float a2 = -expf(A_log[d * 16 + n]) * LOG2E;
    float sval[16], wv[16];
    #pragma unroll
    for (int i = 0; i < 16; ++i) {
        int c = seg * 16 + i;
        sval[i] = S[((b * NC + c) * 16 + n) * 512 + d];
        wv[i]   = exp2f(a2 * sdt[(b * NC + c) * 512 + d]);
    }
    float h = 0.f;
    int o0 = ((b * 16 + n) * 16) * 512 + d;
    for (int s = 0; s < seg; ++s)
        h = Wsg[o0 + s * 512] * h + Ssg[o0 + s * 512];
    #pragma unroll
    for (int i = 0; i < 16; ++i) {
        int c = seg * 16 + i;
        S[((b * NC + c) * 16 + n) * 512 + d] = h;
        h = wv[i] * h + sval[i];
    }
}

// ---------------- scan phase C: replay + skip + SiLU gate -> bf16 ----------
// grid 512 = (b, ch); CT=16
__global__ __launch_bounds__(512) void k_scanC(const ushort_t* __restrict__ dtp,
                                               const ushort_t* __restrict__ xcb,
                                               const float* __restrict__ Bm,
                                               const float* __restrict__ Cm,
                                               const float* __restrict__ A_log,
                                               const float* __restrict__ hinit,
                                               const float* __restrict__ Dskip,
                                               const ushort_t* __restrict__ zb,
                                               ushort_t* __restrict__ yact) {
    int b = blockIdx.x >> 8;
    int ch = blockIdx.x & 255;
    int d = threadIdx.x;
    __shared__ float Bb[CT][16], Cb[CT][16];
    if (threadIdx.x < 256) {
        int t = threadIdx.x >> 4, n = threadIdx.x & 15;
        int li = ((b << 12) + ch * CT + t) * 16 + n;
        Bb[t][n] = Bm[li];
        Cb[t][n] = Cm[li];
    }
    __syncthreads();
    int base = ((b << 12) + ch * CT) * 512 + d;
    float dv_[CT], xv_[CT], zv_[CT];
    #pragma unroll
    for (int t = 0; t < CT; ++t) {
        dv_[t] = bf2f(dtp[base + t * 512]);
        xv_[t] = bf2f(xcb[base + t * 512]);
        zv_[t] = bf2f(zb[base + t * 512]);
    }
    float a2[16], h[16];
    #pragma unroll
    for (int n = 0; n < 16; ++n) a2[n] = -expf(A_log[d * 16 + n]) * LOG2E;
    int hi = ((b * NC + ch) * 16) * 512 + d;
    #pragma unroll
    for (int n = 0; n < 16; ++n) h[n] = hinit[hi + n * 512];
    float Dsk = Dskip[d];
    #pragma unroll
    for (int t = 0; t < CT; ++t) {
        float dv = dv_[t];
        float xv = xv_[t];
        float zv = zv_[t];
        float dx = dv * xv;
        float y = 0.f;
        #pragma unroll
        for (int n = 0; n < 16; ++n) {
            float w = exp2f(dv * a2[n]);
            h[n] = w * h[n] + dx * Bb[t][n];
            y += h[n] * Cb[t][n];
        }
        y += xv * Dsk;
        float sig = 1.f / (1.f + expf(-zv));
        yact[base + t * 512] = f2bf(y * zv * sig);
    }
}

// ---------------- GEMM3 (MFMA bf16): out = yact @ W_out, transposed store --
__global__ __launch_bounds__(256) void k_gemm3(const ushort_t* __restrict__ Abf,
                                               const ushort_t* __restrict__ Wt3,
                                               float* __restrict__ out) {
    __shared__ ushort_t As[128][40];
    __shared__ ushort_t Bs[64][40];
    __shared__ float T[64][132];
    int tid = threadIdx.x;
    int m0 = blockIdx.x * 128;
    int n0 = blockIdx.y * 64;
    int lane = tid & 63, w = tid >> 6;
    int wr = w >> 1, wc = w & 1;
    int quad = lane >> 4, lm = lane & 15;
    f32x4 acc[4][2] = {};
    for (int k0 = 0; k0 < 512; k0 += 32) {
        #pragma unroll
        for (int i = 0; i < 2; ++i) {
            int c = i * 256 + tid;
            int r = c >> 2, kq = c & 3;
            *(uint4*)&As[r][kq * 8] = *(const uint4*)&Abf[(m0 + r) * 512 + k0 + kq * 8];
        }
        {
            int r = tid >> 2, kq = tid & 3;
            *(uint4*)&Bs[r][kq * 8] = *(const uint4*)&Wt3[(n0 + r) * 512 + k0 + kq * 8];
        }
        __syncthreads();
        s16x8 af[4], bf_[2];
        #pragma unroll
        for (int mi = 0; mi < 4; ++mi)
            af[mi] = *(const s16x8*)&As[wr * 64 + mi * 16 + lm][quad * 8];
        #pragma unroll
        for (int ni = 0; ni < 2; ++ni)
            bf_[ni] = *(const s16x8*)&Bs[wc * 32 + ni * 16 + lm][quad * 8];
        #pragma unroll
        for (int mi = 0; mi < 4; ++mi)
            #pragma unroll
            for (int ni = 0; ni < 2; ++ni)
                acc[mi][ni] = __builtin_amdgcn_mfma_f32_16x16x32_bf16(
                    af[mi], bf_[ni], acc[mi][ni], 0, 0, 0);
        __syncthreads();
    }
    #pragma unroll
    for (int mi = 0; mi < 4; ++mi)
        #pragma unroll
        for (int ni = 0; ni < 2; ++ni)
            #pragma unroll
            for (int r = 0; r < 4; ++r)
                T[wc * 32 + ni * 16 + lm][wr * 64 + mi * 16 + quad * 4 + r] = acc[mi][ni][r];
    __syncthreads();
    int b = m0 >> 12;
    int l0 = m0 & 4095;
    #pragma unroll
    for (int i = 0; i < 8; ++i) {
        int f = i * 256 + tid;
        int col = f >> 5, lq = f & 31;
        float4 v = *(float4*)&T[col][lq * 4];
        *(float4*)(out + b * (256 * 4096) + (n0 + col) * 4096 + l0 + lq * 4) = v;
    }
}

extern "C" void kernel_launch(void* const* d_in, const int* in_sizes, int n_in,
                              void* d_out, int out_size, void* d_ws, size_t ws_size,
                              hipStream_t stream) {
    const float* x      = (const float*)d_in[0];
    const float* ln_g   = (const float*)d_in[1];
    const float* ln_b   = (const float*)d_in[2];
    const float* W_in   = (const float*)d_in[3];
    const float* conv_w = (const float*)d_in[4];
    const float* conv_b = (const float*)d_in[5];
    const float* W_x    = (const float*)d_in[6];
    const float* W_dt   = (const float*)d_in[7];
    const float* b_dt   = (const float*)d_in[8];
    const float* A_log  = (const float*)d_in[9];
    const float* D_skip = (const float*)d_in[10];
    const float* W_out  = (const float*)d_in[11];
    float* out = (float*)d_out;

    float* ws = (float*)d_ws;
    float* Bm   = ws;                      // 131,072 f
    float* Cm   = Bm + 131072;             // 131,072 f
    float* Sst  = Cm + 131072;             // 4,194,304 f (NC=256; hinit in place)
    float* sdt  = Sst + 4194304;           // 262,144 f
    float* Wsg  = sdt + 262144;            // 262,144 f
    float* Ssg  = Wsg + 262144;            // 262,144 f
    ushort_t* xs_bf = (ushort_t*)(Ssg + 262144);   // 2,097,152 us
    ushort_t* Wt1  = xs_bf + 2097152;      // 262,144 us
    ushort_t* Wt3  = Wt1 + 262144;         // 131,072 us
    ushort_t* Wxt  = Wt3 + 131072;         // 24,576 us (pad to 32,768)
    ushort_t* xinb = Wxt + 32768;          // 4,194,304 us
    ushort_t* zb   = xinb + 4194304;       // 4,194,304 us
    ushort_t* xcb  = zb + 4194304;         // 4,194,304 us
    ushort_t* dtp  = xcb + 4194304;        // 4,194,304 us
    ushort_t* yact = xinb;                 // alias: xinb dead after k_mega

    k_prep <<<dim3(736),   dim3(256), 0, stream>>>(x, ln_g, ln_b, W_in, W_out, W_x,
                                                   xs_bf, Wt1, Wt3, Wxt);
    k_gemm1<<<dim3(64, 8), dim3(256), 0, stream>>>(xs_bf, Wt1, xinb, zb);
    k_mega <<<dim3(256),   dim3(512), 0, stream>>>(xinb, Wxt, W_dt, b_dt, A_log,
                                                   conv_w, conv_b, xcb, dtp, Bm, Cm,
                                                   Sst, sdt);
    k_combA<<<dim3(512),   dim3(512), 0, stream>>>(Sst, sdt, A_log, Wsg, Ssg);
    k_combC<<<dim3(512),   dim3(512), 0, stream>>>(Sst, sdt, A_log, Wsg, Ssg);
    k_scanC<<<dim3(512),   dim3(512), 0, stream>>>(dtp, xcb, Bm, Cm, A_log, Sst,
                                                   D_skip, zb, yact);
    k_gemm3<<<dim3(64, 4), dim3(256), 0, stream>>>(yact, Wt3, out);
}